// Round 2
// baseline (722.946 us; speedup 1.0000x reference)
//
#include <hip/hip_runtime.h>
#include <stdint.h>
#include <stddef.h>

// BAMM attention block, MI355X.  B=8 C=512 Ck=128 H=W=128 DS=4 -> h=w=32 N=1024.
#define Bn   8
#define Cn   512
#define CKn  128
#define Hn   128
#define Nn   1024

typedef float f32x4 __attribute__((ext_vector_type(4)));
typedef short bf16x8 __attribute__((ext_vector_type(8)));

// ---------- helpers ----------
__device__ __forceinline__ uint16_t f2b(float f) {
  uint32_t x = __float_as_uint(f);
  uint32_t r = (x + 0x7FFFu + ((x >> 16) & 1u)) >> 16;
  return (uint16_t)r;
}

__device__ __forceinline__ void gld_lds16(const uint16_t* g, short* lds_base, int lane) {
#if __has_builtin(__builtin_amdgcn_global_load_lds)
  __builtin_amdgcn_global_load_lds(
      (const __attribute__((address_space(1))) void*)g,
      (__attribute__((address_space(3))) void*)lds_base, 16, 0, 0);
#else
  *(bf16x8*)(lds_base + lane * 8) = *(const bf16x8*)g;
#endif
}

// ---------- 128x128 NT GEMM core (m97-style), 256 threads, BK=32 ----------
// A [128 rows][K] (lda), Bt [128 rows][K] (ldb), both k-contiguous.
// 4 waves in 2x2 grid: wave (wr,wc) owns rows wr*64..+63, cols wc*64..+63.
// acc[i][j][rg] -> row wr*64 + i*16 + quad*4 + rg, col wc*64 + j*16 + l16.
__device__ __forceinline__ void gemm128(const uint16_t* __restrict__ A,
                                        const uint16_t* __restrict__ Bt,
                                        int lda, int ldb, int K,
                                        short* As, short* Bs, f32x4 acc[4][4]) {
  const int tid  = threadIdx.x;
  const int lane = tid & 63;
  const int wave = tid >> 6;
  const int quad = lane >> 4, l16 = lane & 15;
  const int rin  = lane >> 2, cc = lane & 3;   // staging: row-in-16, 16B col chunk
  const int wr = wave >> 1, wc = wave & 1;
  for (int kt = 0; kt < K; kt += 32) {
    __syncthreads();                            // prev-iter readers done
    // A tile 128x32: 8 instrs (2/wave)
    gld_lds16(A  + (size_t)(wave * 32 +      rin) * lda + kt + cc * 8, As + wave * 1024,       lane);
    gld_lds16(A  + (size_t)(wave * 32 + 16 + rin) * lda + kt + cc * 8, As + wave * 1024 + 512, lane);
    // B tile 128x32: 8 instrs (2/wave)
    gld_lds16(Bt + (size_t)(wave * 32 +      rin) * ldb + kt + cc * 8, Bs + wave * 1024,       lane);
    gld_lds16(Bt + (size_t)(wave * 32 + 16 + rin) * ldb + kt + cc * 8, Bs + wave * 1024 + 512, lane);
    __syncthreads();                            // drains vmcnt -> LDS visible
    bf16x8 af[4], bfr[4];
#pragma unroll
    for (int i = 0; i < 4; ++i)
      af[i] = *(const bf16x8*)(As + (wr * 64 + i * 16 + l16) * 32 + quad * 8);
#pragma unroll
    for (int j = 0; j < 4; ++j)
      bfr[j] = *(const bf16x8*)(Bs + (wc * 64 + j * 16 + l16) * 32 + quad * 8);
#pragma unroll
    for (int i = 0; i < 4; ++i)
#pragma unroll
      for (int j = 0; j < 4; ++j)
        acc[i][j] = __builtin_amdgcn_mfma_f32_16x16x32_bf16(af[i], bfr[j], acc[i][j], 0, 0, 0);
  }
}

#define EPI_VARS \
  const int lane = threadIdx.x & 63; const int wave = threadIdx.x >> 6; \
  const int quad = lane >> 4, l16 = lane & 15; \
  const int wr = wave >> 1, wc = wave & 1;

// ---------- kernel 1: weights fp32 -> bf16 ----------
__global__ __launch_bounds__(256) void wconv_kernel(
    const float* __restrict__ Wq, const float* __restrict__ Wk, const float* __restrict__ Wv,
    uint16_t* __restrict__ Wqb, uint16_t* __restrict__ Wkb, uint16_t* __restrict__ Wvb) {
  int i = blockIdx.x * 256 + threadIdx.x;
  if (i < CKn * Cn) { Wqb[i] = f2b(Wq[i]); Wkb[i] = f2b(Wk[i]); }
  Wvb[i] = f2b(Wv[i]);
}

// ---------- kernel 2: 4x4 avg-pool + transpose to [b][n][c] bf16 ----------
__global__ __launch_bounds__(1024) void pool_kernel(
    const float* __restrict__ input, const float* __restrict__ c2,
    uint16_t* __restrict__ xT, uint16_t* __restrict__ yT) {
  const int cblk = blockIdx.x, ph = blockIdx.y;
  const int b = blockIdx.z >> 1, src = blockIdx.z & 1;
  const float* in = src ? c2 : input;
  uint16_t* out = src ? yT : xT;
  const int tw = threadIdx.x & 31, tc = threadIdx.x >> 5;
  const int c = cblk * 32 + tc;
  const float* p = in + (((size_t)(b * Cn + c) * Hn) + ph * 4) * Hn + tw * 4;
  float s = 0.f;
#pragma unroll
  for (int r = 0; r < 4; ++r) {
    float4 t = *(const float4*)(p + (size_t)r * Hn);
    s += t.x + t.y + t.z + t.w;
  }
  __shared__ float tile[32][33];
  tile[tw][tc] = s * 0.0625f;
  __syncthreads();
  const int tn = threadIdx.x >> 5, tcc = threadIdx.x & 31;
  out[((size_t)b * Nn + ph * 32 + tn) * Cn + cblk * 32 + tcc] = f2b(tile[tn][tcc]);
}

// ---------- kernel 3: qkv GEMMs (NT, 128x128 tiles) ----------
// grid (48, 8): x = mt*8+nt, mt 0: q, 1: k, 2-5: v ; y = b
__global__ __launch_bounds__(256) void qkv_kernel(
    const uint16_t* __restrict__ Wqb, const uint16_t* __restrict__ Wkb, const uint16_t* __restrict__ Wvb,
    const float* __restrict__ bq, const float* __restrict__ bk, const float* __restrict__ bv,
    const uint16_t* __restrict__ xT, const uint16_t* __restrict__ yT,
    uint16_t* __restrict__ qT, uint16_t* __restrict__ kT, uint16_t* __restrict__ vm) {
  __shared__ short As[4096], Bs[4096];
  const int b = blockIdx.y;
  const int r = blockIdx.x;
  const int mt = r >> 3, nt = r & 7;
  int op, m0; const uint16_t* A; const float* bias;
  if (mt == 0)      { op = 0; m0 = 0;              A = Wqb;                     bias = bq; }
  else if (mt == 1) { op = 1; m0 = 0;              A = Wkb;                     bias = bk; }
  else              { op = 2; m0 = (mt - 2) * 128; A = Wvb + (size_t)m0 * Cn;   bias = bv; }
  const uint16_t* Bt = ((op == 0) ? xT : yT) + (size_t)b * Nn * Cn + (size_t)nt * 128 * Cn;
  f32x4 acc[4][4];
#pragma unroll
  for (int i = 0; i < 4; ++i)
#pragma unroll
    for (int j = 0; j < 4; ++j) acc[i][j] = (f32x4)0.f;
  gemm128(A, Bt, Cn, Cn, Cn, As, Bs, acc);
  EPI_VARS;
#pragma unroll
  for (int i = 0; i < 4; ++i)
#pragma unroll
    for (int j = 0; j < 4; ++j)
#pragma unroll
      for (int rg = 0; rg < 4; ++rg) {
        int m = m0 + wr * 64 + i * 16 + quad * 4 + rg;
        int n = nt * 128 + wc * 64 + j * 16 + l16;
        float val = acc[i][j][rg] + bias[m];
        if (op == 2) vm[(size_t)(b * Cn + m) * Nn + n] = f2b(val);
        else {
          uint16_t* dst = (op == 0) ? qT : kT;
          dst[(size_t)(b * Nn + n) * CKn + m] = f2b(val);
        }
      }
}

// ---------- kernel 4: fused energy + softmax -> attn bf16 ----------
// grid (64, 8): block = 16 energy rows (n0=bx*16) x all 1024 cols, b = by.
// 1024 threads = 16 waves; wave w owns cols w*64..w*64+63.  K=128 read
// directly from L2 (q/k per batch = 256 KB each, L2-resident); no LDS staging.
// acc[j][rg] -> row n0 + quad*4 + rg, col w*64 + j*16 + l16.
__global__ __launch_bounds__(1024) void esm_kernel(
    const uint16_t* __restrict__ qT, const uint16_t* __restrict__ kT,
    uint16_t* __restrict__ attn) {
  const int b = blockIdx.y, n0 = blockIdx.x * 16;
  const int tid = threadIdx.x, lane = tid & 63, w = tid >> 6;
  const int quad = lane >> 4, l16 = lane & 15;
  const uint16_t* qb = qT + (size_t)(b * Nn + n0) * CKn;
  const uint16_t* kb = kT + (size_t)(b * Nn + w * 64) * CKn;
  f32x4 acc[4];
#pragma unroll
  for (int j = 0; j < 4; ++j) acc[j] = (f32x4)0.f;
#pragma unroll
  for (int kt = 0; kt < CKn; kt += 32) {
    bf16x8 af = *(const bf16x8*)(qb + (size_t)l16 * CKn + kt + quad * 8);
    bf16x8 bfr[4];
#pragma unroll
    for (int j = 0; j < 4; ++j)
      bfr[j] = *(const bf16x8*)(kb + (size_t)(j * 16 + l16) * CKn + kt + quad * 8);
#pragma unroll
    for (int j = 0; j < 4; ++j)
      acc[j] = __builtin_amdgcn_mfma_f32_16x16x32_bf16(af, bfr[j], acc[j], 0, 0, 0);
  }
  const float scale = 0.08838834764831845f;  // 128^-0.5
#pragma unroll
  for (int j = 0; j < 4; ++j) acc[j] *= scale;

  __shared__ float red[16][16];   // [row][wave]
  __shared__ float gout[16];
  // ---- row max (over cols): in-lane over j, then over l16 (16 lanes share row) ----
  float mx[4];
#pragma unroll
  for (int rg = 0; rg < 4; ++rg) {
    mx[rg] = fmaxf(fmaxf(acc[0][rg], acc[1][rg]), fmaxf(acc[2][rg], acc[3][rg]));
#pragma unroll
    for (int off = 1; off < 16; off <<= 1) mx[rg] = fmaxf(mx[rg], __shfl_xor(mx[rg], off, 64));
  }
  if (l16 == 0) {
#pragma unroll
    for (int rg = 0; rg < 4; ++rg) red[quad * 4 + rg][w] = mx[rg];
  }
  __syncthreads();
  if (tid < 16) {
    float g = -3.4e38f;
#pragma unroll
    for (int ww = 0; ww < 16; ++ww) g = fmaxf(g, red[tid][ww]);
    gout[tid] = g;
  }
  __syncthreads();
  float rmax[4];
#pragma unroll
  for (int rg = 0; rg < 4; ++rg) rmax[rg] = gout[quad * 4 + rg];
  // ---- exp + row sum ----
  float sm[4] = {0.f, 0.f, 0.f, 0.f};
#pragma unroll
  for (int j = 0; j < 4; ++j)
#pragma unroll
    for (int rg = 0; rg < 4; ++rg) {
      float p = __expf(acc[j][rg] - rmax[rg]);
      acc[j][rg] = p;
      sm[rg] += p;
    }
#pragma unroll
  for (int rg = 0; rg < 4; ++rg)
#pragma unroll
    for (int off = 1; off < 16; off <<= 1) sm[rg] += __shfl_xor(sm[rg], off, 64);
  if (l16 == 0) {
#pragma unroll
    for (int rg = 0; rg < 4; ++rg) red[quad * 4 + rg][w] = sm[rg];
  }
  __syncthreads();
  if (tid < 16) {
    float s = 0.f;
#pragma unroll
    for (int ww = 0; ww < 16; ++ww) s += red[tid][ww];
    gout[tid] = 1.f / s;
  }
  __syncthreads();
  // ---- write attn bf16 ----
#pragma unroll
  for (int rg = 0; rg < 4; ++rg) {
    float inv = gout[quad * 4 + rg];
    uint16_t* arow = attn + (size_t)(b * Nn + n0 + quad * 4 + rg) * Nn + w * 64;
#pragma unroll
    for (int j = 0; j < 4; ++j) arow[j * 16 + l16] = f2b(acc[j][rg] * inv);
  }
}

// ---------- kernel 5: out = upsample4(v @ attn^T) + c2 (NT, K=1024, fused epilogue) ----------
// grid (32, 8): x = mt*8+nt (mt over C/128, nt over N/128), y = b
__global__ __launch_bounds__(256) void outup_kernel(
    const uint16_t* __restrict__ vm, const uint16_t* __restrict__ attn,
    const float* __restrict__ c2, float* __restrict__ out) {
  __shared__ short As[4096], Bs[4096];
  const int b = blockIdx.y;
  const int r = blockIdx.x, mt = r >> 3, nt = r & 7;
  const uint16_t* A  = vm   + (size_t)b * Cn * Nn + (size_t)mt * 128 * Nn;
  const uint16_t* Bt = attn + (size_t)b * Nn * Nn + (size_t)nt * 128 * Nn;
  f32x4 acc[4][4];
#pragma unroll
  for (int i = 0; i < 4; ++i)
#pragma unroll
    for (int j = 0; j < 4; ++j) acc[i][j] = (f32x4)0.f;
  gemm128(A, Bt, Nn, Nn, Nn, As, Bs, acc);
  EPI_VARS;
  // each acc element (c,n) -> 4x4 output pixels; lanes l16 consecutive in n
  // -> pw consecutive -> 256 B contiguous per 16 lanes: coalesced float4 RMW.
#pragma unroll
  for (int i = 0; i < 4; ++i)
#pragma unroll
    for (int j = 0; j < 4; ++j) {
      const int n  = nt * 128 + wc * 64 + j * 16 + l16;
      const int ph = n >> 5, pw = n & 31;
#pragma unroll
      for (int rg = 0; rg < 4; ++rg) {
        const int c = mt * 128 + wr * 64 + i * 16 + quad * 4 + rg;
        const float v = acc[i][j][rg];
        const size_t base = (((size_t)(b * Cn + c) * Hn) + ph * 4) * Hn + pw * 4;
#pragma unroll
        for (int rr = 0; rr < 4; ++rr) {
          float4 t4 = *(const float4*)(c2 + base + (size_t)rr * Hn);
          t4.x += v; t4.y += v; t4.z += v; t4.w += v;
          *(float4*)(out + base + (size_t)rr * Hn) = t4;
        }
      }
    }
}

// ---------- launch ----------
extern "C" void kernel_launch(void* const* d_in, const int* in_sizes, int n_in,
                              void* d_out, int out_size, void* d_ws, size_t ws_size,
                              hipStream_t stream) {
  const float* input = (const float*)d_in[0];
  const float* c2    = (const float*)d_in[1];
  const float* Wq    = (const float*)d_in[2];
  const float* bq    = (const float*)d_in[3];
  const float* Wk    = (const float*)d_in[4];
  const float* bk    = (const float*)d_in[5];
  const float* Wv    = (const float*)d_in[6];
  const float* bv    = (const float*)d_in[7];
  float* out = (float*)d_out;
  uint8_t* ws = (uint8_t*)d_ws;

  uint16_t* xT   = (uint16_t*)(ws + 0);            //  8 MB [8][1024][512]
  uint16_t* yT   = (uint16_t*)(ws + 8388608);      //  8 MB
  uint16_t* Wqb  = (uint16_t*)(ws + 16777216);     // 128 KB
  uint16_t* Wkb  = (uint16_t*)(ws + 16908288);     // 128 KB
  uint16_t* Wvb  = (uint16_t*)(ws + 17039360);     // 512 KB
  uint16_t* qT   = (uint16_t*)(ws + 17563648);     //  2 MB [8][1024][128]
  uint16_t* kT   = (uint16_t*)(ws + 19660800);     //  2 MB
  uint16_t* vm   = (uint16_t*)(ws + 21757952);     //  8 MB [8][512][1024]
  uint16_t* attn = (uint16_t*)(ws + 30146560);     // 16 MB [8][1024][1024] bf16
  // total 46,923,776 bytes (eng/osm eliminated)

  hipLaunchKernelGGL(wconv_kernel, dim3(1024), dim3(256), 0, stream,
                     Wq, Wk, Wv, Wqb, Wkb, Wvb);
  hipLaunchKernelGGL(pool_kernel, dim3(16, 32, 16), dim3(1024), 0, stream,
                     input, c2, xT, yT);
  hipLaunchKernelGGL(qkv_kernel, dim3(48, 8), dim3(256), 0, stream,
                     Wqb, Wkb, Wvb, bq, bk, bv, xT, yT, qT, kT, vm);
  hipLaunchKernelGGL(esm_kernel, dim3(64, 8), dim3(1024), 0, stream, qT, kT, attn);
  hipLaunchKernelGGL(outup_kernel, dim3(32, 8), dim3(256), 0, stream,
                     vm, attn, c2, out);
}

// Round 3
// 711.530 us; speedup vs baseline: 1.0160x; 1.0160x over previous
//
#include <hip/hip_runtime.h>
#include <stdint.h>
#include <stddef.h>

// BAMM attention block, MI355X.  B=8 C=512 Ck=128 H=W=128 DS=4 -> h=w=32 N=1024.
#define Bn   8
#define Cn   512
#define CKn  128
#define Hn   128
#define Nn   1024

typedef float f32x4 __attribute__((ext_vector_type(4)));
typedef short bf16x8 __attribute__((ext_vector_type(8)));

// ---------- helpers ----------
__device__ __forceinline__ uint16_t f2b(float f) {
  uint32_t x = __float_as_uint(f);
  uint32_t r = (x + 0x7FFFu + ((x >> 16) & 1u)) >> 16;
  return (uint16_t)r;
}

__device__ __forceinline__ void gld_lds16(const uint16_t* g, short* lds_base, int lane) {
#if __has_builtin(__builtin_amdgcn_global_load_lds)
  __builtin_amdgcn_global_load_lds(
      (const __attribute__((address_space(1))) void*)g,
      (__attribute__((address_space(3))) void*)lds_base, 16, 0, 0);
#else
  *(bf16x8*)(lds_base + lane * 8) = *(const bf16x8*)g;
#endif
}

// ---------- 128x128 NT GEMM core, 256 threads, BK=32 ----------
// A [128 rows][K] (lda), Bt [128 rows][K] (ldb), both k-contiguous.
// 4 waves in 2x2 grid: wave (wr,wc) owns rows wr*64..+63, cols wc*64..+63.
// acc[i][j][rg] -> row wr*64 + i*16 + quad*4 + rg, col wc*64 + j*16 + l16.
__device__ __forceinline__ void gemm128(const uint16_t* __restrict__ A,
                                        const uint16_t* __restrict__ Bt,
                                        int lda, int ldb, int K,
                                        short* As, short* Bs, f32x4 acc[4][4]) {
  const int tid  = threadIdx.x;
  const int lane = tid & 63;
  const int wave = tid >> 6;
  const int quad = lane >> 4, l16 = lane & 15;
  const int rin  = lane >> 2, cc = lane & 3;   // staging: row-in-16, 16B col chunk
  const int wr = wave >> 1, wc = wave & 1;
  for (int kt = 0; kt < K; kt += 32) {
    __syncthreads();                            // prev-iter readers done
    // A tile 128x32: 8 instrs (2/wave)
    gld_lds16(A  + (size_t)(wave * 32 +      rin) * lda + kt + cc * 8, As + wave * 1024,       lane);
    gld_lds16(A  + (size_t)(wave * 32 + 16 + rin) * lda + kt + cc * 8, As + wave * 1024 + 512, lane);
    // B tile 128x32: 8 instrs (2/wave)
    gld_lds16(Bt + (size_t)(wave * 32 +      rin) * ldb + kt + cc * 8, Bs + wave * 1024,       lane);
    gld_lds16(Bt + (size_t)(wave * 32 + 16 + rin) * ldb + kt + cc * 8, Bs + wave * 1024 + 512, lane);
    __syncthreads();                            // drains vmcnt -> LDS visible
    bf16x8 af[4], bfr[4];
#pragma unroll
    for (int i = 0; i < 4; ++i)
      af[i] = *(const bf16x8*)(As + (wr * 64 + i * 16 + l16) * 32 + quad * 8);
#pragma unroll
    for (int j = 0; j < 4; ++j)
      bfr[j] = *(const bf16x8*)(Bs + (wc * 64 + j * 16 + l16) * 32 + quad * 8);
#pragma unroll
    for (int i = 0; i < 4; ++i)
#pragma unroll
      for (int j = 0; j < 4; ++j)
        acc[i][j] = __builtin_amdgcn_mfma_f32_16x16x32_bf16(af[i], bfr[j], acc[i][j], 0, 0, 0);
  }
}

// ---------- 64x128 NT GEMM core (known-good, 2 blocks/CU at grid 512) ----------
// 4 waves: wave w owns output rows w*16..w*16+15, all 128 cols.
// acc[j][rg] -> row w*16 + quad*4 + rg, col j*16 + l16.
__device__ __forceinline__ void gemm64x128(const uint16_t* __restrict__ A,
                                           const uint16_t* __restrict__ Bt,
                                           int lda, int ldb, int K,
                                           short* As, short* Bs, f32x4 acc[8]) {
  const int tid  = threadIdx.x;
  const int lane = tid & 63;
  const int wave = tid >> 6;
  const int quad = lane >> 4, l16 = lane & 15;
  const int rin  = lane >> 2, cc = lane & 3;
  for (int kt = 0; kt < K; kt += 32) {
    __syncthreads();
    gld_lds16(A + (size_t)(wave * 16 + rin) * lda + kt + cc * 8, As + wave * 512, lane);
    gld_lds16(Bt + (size_t)(wave * 32 + rin) * ldb + kt + cc * 8, Bs + wave * 1024, lane);
    gld_lds16(Bt + (size_t)(wave * 32 + 16 + rin) * ldb + kt + cc * 8, Bs + wave * 1024 + 512, lane);
    __syncthreads();
    bf16x8 af = *(const bf16x8*)(As + (wave * 16 + l16) * 32 + quad * 8);
#pragma unroll
    for (int j = 0; j < 8; ++j) {
      bf16x8 bfr = *(const bf16x8*)(Bs + (j * 16 + l16) * 32 + quad * 8);
      acc[j] = __builtin_amdgcn_mfma_f32_16x16x32_bf16(af, bfr, acc[j], 0, 0, 0);
    }
  }
}

#define EPI_VARS \
  const int lane = threadIdx.x & 63; const int wave = threadIdx.x >> 6; \
  const int quad = lane >> 4, l16 = lane & 15; \
  const int wr = wave >> 1, wc = wave & 1;

// ---------- kernel 1: weights fp32 -> bf16 ----------
__global__ __launch_bounds__(256) void wconv_kernel(
    const float* __restrict__ Wq, const float* __restrict__ Wk, const float* __restrict__ Wv,
    uint16_t* __restrict__ Wqb, uint16_t* __restrict__ Wkb, uint16_t* __restrict__ Wvb) {
  int i = blockIdx.x * 256 + threadIdx.x;
  if (i < CKn * Cn) { Wqb[i] = f2b(Wq[i]); Wkb[i] = f2b(Wk[i]); }
  Wvb[i] = f2b(Wv[i]);
}

// ---------- kernel 2: 4x4 avg-pool + transpose to [b][n][c] bf16 ----------
__global__ __launch_bounds__(1024) void pool_kernel(
    const float* __restrict__ input, const float* __restrict__ c2,
    uint16_t* __restrict__ xT, uint16_t* __restrict__ yT) {
  const int cblk = blockIdx.x, ph = blockIdx.y;
  const int b = blockIdx.z >> 1, src = blockIdx.z & 1;
  const float* in = src ? c2 : input;
  uint16_t* out = src ? yT : xT;
  const int tw = threadIdx.x & 31, tc = threadIdx.x >> 5;
  const int c = cblk * 32 + tc;
  const float* p = in + (((size_t)(b * Cn + c) * Hn) + ph * 4) * Hn + tw * 4;
  float s = 0.f;
#pragma unroll
  for (int r = 0; r < 4; ++r) {
    float4 t = *(const float4*)(p + (size_t)r * Hn);
    s += t.x + t.y + t.z + t.w;
  }
  __shared__ float tile[32][33];
  tile[tw][tc] = s * 0.0625f;
  __syncthreads();
  const int tn = threadIdx.x >> 5, tcc = threadIdx.x & 31;
  out[((size_t)b * Nn + ph * 32 + tn) * Cn + cblk * 32 + tcc] = f2b(tile[tn][tcc]);
}

// ---------- kernel 3: qkv GEMMs (NT, 128x128 tiles) ----------
// grid (48, 8): x = mt*8+nt, mt 0: q, 1: k, 2-5: v ; y = b
__global__ __launch_bounds__(256) void qkv_kernel(
    const uint16_t* __restrict__ Wqb, const uint16_t* __restrict__ Wkb, const uint16_t* __restrict__ Wvb,
    const float* __restrict__ bq, const float* __restrict__ bk, const float* __restrict__ bv,
    const uint16_t* __restrict__ xT, const uint16_t* __restrict__ yT,
    uint16_t* __restrict__ qT, uint16_t* __restrict__ kT, uint16_t* __restrict__ vm) {
  __shared__ short As[4096], Bs[4096];
  const int b = blockIdx.y;
  const int r = blockIdx.x;
  const int mt = r >> 3, nt = r & 7;
  int op, m0; const uint16_t* A; const float* bias;
  if (mt == 0)      { op = 0; m0 = 0;              A = Wqb;                     bias = bq; }
  else if (mt == 1) { op = 1; m0 = 0;              A = Wkb;                     bias = bk; }
  else              { op = 2; m0 = (mt - 2) * 128; A = Wvb + (size_t)m0 * Cn;   bias = bv; }
  const uint16_t* Bt = ((op == 0) ? xT : yT) + (size_t)b * Nn * Cn + (size_t)nt * 128 * Cn;
  f32x4 acc[4][4];
#pragma unroll
  for (int i = 0; i < 4; ++i)
#pragma unroll
    for (int j = 0; j < 4; ++j) acc[i][j] = (f32x4)0.f;
  gemm128(A, Bt, Cn, Cn, Cn, As, Bs, acc);
  EPI_VARS;
#pragma unroll
  for (int i = 0; i < 4; ++i)
#pragma unroll
    for (int j = 0; j < 4; ++j)
#pragma unroll
      for (int rg = 0; rg < 4; ++rg) {
        int m = m0 + wr * 64 + i * 16 + quad * 4 + rg;
        int n = nt * 128 + wc * 64 + j * 16 + l16;
        float val = acc[i][j][rg] + bias[m];
        if (op == 2) vm[(size_t)(b * Cn + m) * Nn + n] = f2b(val);
        else {
          uint16_t* dst = (op == 0) ? qT : kT;
          dst[(size_t)(b * Nn + n) * CKn + m] = f2b(val);
        }
      }
}

// ---------- kernel 4: fused energy + softmax -> attn bf16 ----------
// grid (64, 8): block = 16 energy rows (n0=bx*16) x all 1024 cols, b = by.
// 1024 threads = 16 waves; wave w owns cols w*64..w*64+63.  K=128 read
// directly from L2 (q/k per batch = 256 KB each); no LDS staging, no K-loop barriers.
// acc[j][rg] -> row n0 + quad*4 + rg, col w*64 + j*16 + l16.
__global__ __launch_bounds__(1024) void esm_kernel(
    const uint16_t* __restrict__ qT, const uint16_t* __restrict__ kT,
    uint16_t* __restrict__ attn) {
  const int b = blockIdx.y, n0 = blockIdx.x * 16;
  const int tid = threadIdx.x, lane = tid & 63, w = tid >> 6;
  const int quad = lane >> 4, l16 = lane & 15;
  const uint16_t* qb = qT + (size_t)(b * Nn + n0) * CKn;
  const uint16_t* kb = kT + (size_t)(b * Nn + w * 64) * CKn;
  f32x4 acc[4];
#pragma unroll
  for (int j = 0; j < 4; ++j) acc[j] = (f32x4)0.f;
#pragma unroll
  for (int kt = 0; kt < CKn; kt += 32) {
    bf16x8 af = *(const bf16x8*)(qb + (size_t)l16 * CKn + kt + quad * 8);
    bf16x8 bfr[4];
#pragma unroll
    for (int j = 0; j < 4; ++j)
      bfr[j] = *(const bf16x8*)(kb + (size_t)(j * 16 + l16) * CKn + kt + quad * 8);
#pragma unroll
    for (int j = 0; j < 4; ++j)
      acc[j] = __builtin_amdgcn_mfma_f32_16x16x32_bf16(af, bfr[j], acc[j], 0, 0, 0);
  }
  const float scale = 0.08838834764831845f;  // 128^-0.5
#pragma unroll
  for (int j = 0; j < 4; ++j) acc[j] *= scale;

  __shared__ float red[16][16];   // [row][wave]
  __shared__ float gout[16];
  // ---- row max (over cols): in-lane over j, then over l16 (16 lanes share row) ----
  float mx[4];
#pragma unroll
  for (int rg = 0; rg < 4; ++rg) {
    mx[rg] = fmaxf(fmaxf(acc[0][rg], acc[1][rg]), fmaxf(acc[2][rg], acc[3][rg]));
#pragma unroll
    for (int off = 1; off < 16; off <<= 1) mx[rg] = fmaxf(mx[rg], __shfl_xor(mx[rg], off, 64));
  }
  if (l16 == 0) {
#pragma unroll
    for (int rg = 0; rg < 4; ++rg) red[quad * 4 + rg][w] = mx[rg];
  }
  __syncthreads();
  if (tid < 16) {
    float g = -3.4e38f;
#pragma unroll
    for (int ww = 0; ww < 16; ++ww) g = fmaxf(g, red[tid][ww]);
    gout[tid] = g;
  }
  __syncthreads();
  float rmax[4];
#pragma unroll
  for (int rg = 0; rg < 4; ++rg) rmax[rg] = gout[quad * 4 + rg];
  // ---- exp + row sum ----
  float sm[4] = {0.f, 0.f, 0.f, 0.f};
#pragma unroll
  for (int j = 0; j < 4; ++j)
#pragma unroll
    for (int rg = 0; rg < 4; ++rg) {
      float p = __expf(acc[j][rg] - rmax[rg]);
      acc[j][rg] = p;
      sm[rg] += p;
    }
#pragma unroll
  for (int rg = 0; rg < 4; ++rg)
#pragma unroll
    for (int off = 1; off < 16; off <<= 1) sm[rg] += __shfl_xor(sm[rg], off, 64);
  if (l16 == 0) {
#pragma unroll
    for (int rg = 0; rg < 4; ++rg) red[quad * 4 + rg][w] = sm[rg];
  }
  __syncthreads();
  if (tid < 16) {
    float s = 0.f;
#pragma unroll
    for (int ww = 0; ww < 16; ++ww) s += red[tid][ww];
    gout[tid] = 1.f / s;
  }
  __syncthreads();
  // ---- write attn bf16 ----
#pragma unroll
  for (int rg = 0; rg < 4; ++rg) {
    float inv = gout[quad * 4 + rg];
    uint16_t* arow = attn + (size_t)(b * Nn + n0 + quad * 4 + rg) * Nn + w * 64;
#pragma unroll
    for (int j = 0; j < 4; ++j) arow[j * 16 + l16] = f2b(acc[j][rg] * inv);
  }
}

// ---------- kernel 5: osm = v * attn^T (NT, K=1024) -> fp32 [b][c][n] ----------
// grid 512 = 8 b * 8 mt * 8 nt  (2 blocks/CU for latency hiding)
__global__ __launch_bounds__(256) void outg_kernel(
    const uint16_t* __restrict__ vm, const uint16_t* __restrict__ attn,
    float* __restrict__ osm) {
  __shared__ short As[2048], Bs[4096];
  const int bx = blockIdx.x;
  const int b = bx >> 6, r = bx & 63, mt = r >> 3, nt = r & 7;
  const uint16_t* A  = vm   + (size_t)b * Cn * Nn + (size_t)mt * 64 * Nn;
  const uint16_t* Bt = attn + (size_t)b * Nn * Nn + (size_t)nt * 128 * Nn;
  f32x4 acc[8];
#pragma unroll
  for (int j = 0; j < 8; ++j) acc[j] = (f32x4)0.f;
  gemm64x128(A, Bt, Nn, Nn, Nn, As, Bs, acc);
  EPI_VARS;
  (void)wr; (void)wc;
#pragma unroll
  for (int j = 0; j < 8; ++j)
#pragma unroll
    for (int rg = 0; rg < 4; ++rg) {
      int c = mt * 64 + wave * 16 + quad * 4 + rg;
      int n = nt * 128 + j * 16 + l16;
      osm[(size_t)b * Cn * Nn + (size_t)c * Nn + n] = acc[j][rg];
    }
}

// ---------- kernel 6: nearest 4x upsample + residual (streaming, full occupancy) ----------
// grid 65536 * 256: one float4 of out per thread
__global__ __launch_bounds__(256) void upsample_kernel(
    const float* __restrict__ osm, const float* __restrict__ c2,
    float* __restrict__ out) {
  const int t = blockIdx.x * 256 + threadIdx.x;        // < 2^24
  const int ww4 = t & 31;                              // float4 col (0..31)
  const int hh  = (t >> 5) & 127;
  const int cb  = t >> 12;                             // b*512 + c  (0..4095)
  const int n = (hh >> 2) * 32 + ww4;                  // pooled pixel
  const float val = osm[((size_t)cb << 10) + n];
  const size_t base = (((size_t)cb * Hn) + hh) * Hn + ww4 * 4;
  float4 t4 = *(const float4*)(c2 + base);
  t4.x += val; t4.y += val; t4.z += val; t4.w += val;
  *(float4*)(out + base) = t4;
}

// ---------- launch ----------
extern "C" void kernel_launch(void* const* d_in, const int* in_sizes, int n_in,
                              void* d_out, int out_size, void* d_ws, size_t ws_size,
                              hipStream_t stream) {
  const float* input = (const float*)d_in[0];
  const float* c2    = (const float*)d_in[1];
  const float* Wq    = (const float*)d_in[2];
  const float* bq    = (const float*)d_in[3];
  const float* Wk    = (const float*)d_in[4];
  const float* bk    = (const float*)d_in[5];
  const float* Wv    = (const float*)d_in[6];
  const float* bv    = (const float*)d_in[7];
  float* out = (float*)d_out;
  uint8_t* ws = (uint8_t*)d_ws;

  uint16_t* xT   = (uint16_t*)(ws + 0);            //  8 MB [8][1024][512]
  uint16_t* yT   = (uint16_t*)(ws + 8388608);      //  8 MB
  uint16_t* Wqb  = (uint16_t*)(ws + 16777216);     // 128 KB
  uint16_t* Wkb  = (uint16_t*)(ws + 16908288);     // 128 KB
  uint16_t* Wvb  = (uint16_t*)(ws + 17039360);     // 512 KB
  uint16_t* qT   = (uint16_t*)(ws + 17563648);     //  2 MB [8][1024][128]
  uint16_t* kT   = (uint16_t*)(ws + 19660800);     //  2 MB
  uint16_t* vm   = (uint16_t*)(ws + 21757952);     //  8 MB [8][512][1024]
  uint16_t* attn = (uint16_t*)(ws + 30146560);     // 16 MB [8][1024][1024] bf16
  float*    osm  = (float*)   (ws + 46923776);     // 16 MB [8][512][1024] fp32
  // total 63,700,992 bytes

  hipLaunchKernelGGL(wconv_kernel, dim3(1024), dim3(256), 0, stream,
                     Wq, Wk, Wv, Wqb, Wkb, Wvb);
  hipLaunchKernelGGL(pool_kernel, dim3(16, 32, 16), dim3(1024), 0, stream,
                     input, c2, xT, yT);
  hipLaunchKernelGGL(qkv_kernel, dim3(48, 8), dim3(256), 0, stream,
                     Wqb, Wkb, Wvb, bq, bk, bv, xT, yT, qT, kT, vm);
  hipLaunchKernelGGL(esm_kernel, dim3(64, 8), dim3(1024), 0, stream, qT, kT, attn);
  hipLaunchKernelGGL(outg_kernel, dim3(512), dim3(256), 0, stream, vm, attn, osm);
  hipLaunchKernelGGL(upsample_kernel, dim3(65536), dim3(256), 0, stream, osm, c2, out);
}